// Round 14
// baseline (5282.328 us; speedup 1.0000x reference)
//
#include <hip/hip_runtime.h>

#define SEQL 1024
#define EMB  2048
#define HID  2048
#define G4   8192   // 4*HID
#define NTAG 50
#define NWG  256
#define NGRP 8      // leader groups (32 WGs each)

typedef _Float16 h2v __attribute__((ext_vector_type(2)));
typedef _Float16 h4v __attribute__((ext_vector_type(4)));
typedef __attribute__((ext_vector_type(8))) short bf16x8;   // 8 bf16 = 4 VGPR
typedef __attribute__((ext_vector_type(4))) float f32x4;

#if __has_builtin(__builtin_amdgcn_fdot2)
#define DOT2(a, b, c) __builtin_amdgcn_fdot2((a), (b), (c), false)
#else
#define DOT2(a, b, c) ((c) + (float)(a).x * (float)(b).x + (float)(a).y * (float)(b).y)
#endif
#define SH2(v, i, j) __builtin_shufflevector((v), (v), (i), (j))

__device__ __forceinline__ ushort f2bf_rne(float f) {
    unsigned u = __float_as_uint(f);
    unsigned r = (u + 0x7fffu + ((u >> 16) & 1u)) >> 16;   // round-nearest-even
    return (ushort)r;
}

// ---------------------------------------------------------------------------
// Kernel 1: x_gates = emb[seq] @ W_ih^T + b_ih + b_hh  (bf16 MFMA, unchanged
// from R10 — verified ~40us). Block (0,0) zeroes kernel 2's hslot, group
// flags, and final-phase flags (graph-replay reset; stream-ordered).
// ---------------------------------------------------------------------------
__global__ __launch_bounds__(256) void gemm_xgates(
    const int* __restrict__ seq, const float* __restrict__ emb,
    const float* __restrict__ Wih, const float* __restrict__ bih,
    const float* __restrict__ bhh, float* __restrict__ xg,
    unsigned int* __restrict__ hslot, unsigned int* __restrict__ gflag,
    int* __restrict__ flags)
{
    if (blockIdx.x == 0 && blockIdx.y == 0) {
        for (int i = threadIdx.x; i < 2 * HID; i += 256) hslot[i] = 0;
        if (threadIdx.x < 2 * NGRP * 16) gflag[threadIdx.x] = 0;
        if (threadIdx.x < NWG) flags[threadIdx.x] = 0;
    }

    constexpr int BM = 128, BN = 128, BK = 64;
    __shared__ __align__(16) ushort Al[BM][BK];   // bf16, chunk-XOR swizzled
    __shared__ __align__(16) ushort Bl[BN][BK];
    __shared__ int srow[BM];

    const int tid = threadIdx.x;
    const int bn = blockIdx.x, bm = blockIdx.y;

    if (tid < BM) srow[tid] = seq[bm * BM + tid];
    __syncthreads();

    const int lane = tid & 63;
    const int wave = tid >> 6;          // 0..3
    const int wm = (wave >> 1) * 64;
    const int wn = (wave & 1) * 64;
    const int srw = tid >> 1;           // staging row 0..127
    const int skh = (tid & 1) * 32;     // staging k-offset 0/32
    const int cb  = skh >> 3;           // base chunk 0/4

    f32x4 acc[4][4] = {};

    for (int k0 = 0; k0 < EMB; k0 += BK) {
        const float* ap = emb + (size_t)srow[srw] * EMB + k0 + skh;
        const float* bp = Wih + (size_t)(bn * BN + srw) * EMB + k0 + skh;
        #pragma unroll
        for (int c = 0; c < 4; ++c) {
            float4 a0 = *(const float4*)(ap + 8 * c);
            float4 a1 = *(const float4*)(ap + 8 * c + 4);
            bf16x8 av;
            av[0] = (short)f2bf_rne(a0.x); av[1] = (short)f2bf_rne(a0.y);
            av[2] = (short)f2bf_rne(a0.z); av[3] = (short)f2bf_rne(a0.w);
            av[4] = (short)f2bf_rne(a1.x); av[5] = (short)f2bf_rne(a1.y);
            av[6] = (short)f2bf_rne(a1.z); av[7] = (short)f2bf_rne(a1.w);
            *(bf16x8*)&Al[srw][8 * ((cb + c) ^ (srw & 7))] = av;

            float4 b0 = *(const float4*)(bp + 8 * c);
            float4 b1 = *(const float4*)(bp + 8 * c + 4);
            bf16x8 bv;
            bv[0] = (short)f2bf_rne(b0.x); bv[1] = (short)f2bf_rne(b0.y);
            bv[2] = (short)f2bf_rne(b0.z); bv[3] = (short)f2bf_rne(b0.w);
            bv[4] = (short)f2bf_rne(b1.x); bv[5] = (short)f2bf_rne(b1.y);
            bv[6] = (short)f2bf_rne(b1.z); bv[7] = (short)f2bf_rne(b1.w);
            *(bf16x8*)&Bl[srw][8 * ((cb + c) ^ (srw & 7))] = bv;
        }
        __syncthreads();

        const int kg = lane >> 4;        // k-group 0..3
        #pragma unroll
        for (int ks = 0; ks < 2; ++ks) {
            bf16x8 af[4], bfr[4];
            #pragma unroll
            for (int f = 0; f < 4; ++f) {
                const int ra = wm + f * 16 + (lane & 15);
                af[f]  = *(const bf16x8*)&Al[ra][8 * ((ks * 4 + kg) ^ (ra & 7))];
                const int rb = wn + f * 16 + (lane & 15);
                bfr[f] = *(const bf16x8*)&Bl[rb][8 * ((ks * 4 + kg) ^ (rb & 7))];
            }
            #pragma unroll
            for (int i = 0; i < 4; ++i)
                #pragma unroll
                for (int j2 = 0; j2 < 4; ++j2)
                    acc[i][j2] = __builtin_amdgcn_mfma_f32_16x16x32_bf16(
                        af[i], bfr[j2], acc[i][j2], 0, 0, 0);
        }
        __syncthreads();
    }

    float bb[4];
    #pragma unroll
    for (int j2 = 0; j2 < 4; ++j2) {
        const int col = bn * BN + wn + j2 * 16 + (lane & 15);
        bb[j2] = bih[col] + bhh[col];
    }
    #pragma unroll
    for (int i = 0; i < 4; ++i) {
        #pragma unroll
        for (int e = 0; e < 4; ++e) {
            const int row = bm * BM + wm + i * 16 + (lane >> 4) * 4 + e;
            #pragma unroll
            for (int j2 = 0; j2 < 4; ++j2) {
                const int col = bn * BN + wn + j2 * 16 + (lane & 15);
                xg[(size_t)row * G4 + col] = acc[i][j2][e] + bb[j2];
            }
        }
    }
}

// ---------------------------------------------------------------------------
// L3-direct (sc0 sc1) helpers. Compiler constraint notes (R12/R13): 128-bit
// tuple operands work as asm OUTPUTS ("=v") but not as INPUTS ("v") and not
// tied ("+v") — so 16B stores are expressed as 4 dword stores w/ offsets.
// ---------------------------------------------------------------------------
__device__ __forceinline__ uint4 ld_u4_l3(const void* p) {
    uint4 r;
    asm volatile("global_load_dwordx4 %0, %1, off sc0 sc1\n\ts_waitcnt vmcnt(0)"
                 : "=v"(r) : "v"(p) : "memory");
    return r;
}
__device__ __forceinline__ int ld_i32_l3(const void* p) {
    int r;
    asm volatile("global_load_dword %0, %1, off sc0 sc1\n\ts_waitcnt vmcnt(0)"
                 : "=v"(r) : "v"(p) : "memory");
    return r;
}
__device__ __forceinline__ float ld_f32_l3(const void* p) {
    float r;
    asm volatile("global_load_dword %0, %1, off sc0 sc1\n\ts_waitcnt vmcnt(0)"
                 : "=v"(r) : "v"(p) : "memory");
    return r;
}
__device__ __forceinline__ void st_u4_l3(void* p, uint4 v) {
    asm volatile(
        "global_store_dword %0, %1, off sc0 sc1\n\t"
        "global_store_dword %0, %2, off offset:4 sc0 sc1\n\t"
        "global_store_dword %0, %3, off offset:8 sc0 sc1\n\t"
        "global_store_dword %0, %4, off offset:12 sc0 sc1"
        :: "v"(p), "v"(v.x), "v"(v.y), "v"(v.z), "v"(v.w) : "memory");
}
__device__ __forceinline__ void st_u32_l3(void* p, unsigned int v) {
    asm volatile("global_store_dword %0, %1, off sc0 sc1"
                 :: "v"(p), "v"(v) : "memory");
}
__device__ __forceinline__ void st_f32_l3(void* p, float v) {
    asm volatile("global_store_dword %0, %1, off sc0 sc1"
                 :: "v"(p), "v"(v) : "memory");
}
__device__ __forceinline__ void wait_vm0() {
    asm volatile("s_waitcnt vmcnt(0)" ::: "memory");
}

__device__ __forceinline__ float sigm_(float x) { return 1.0f / (1.0f + __expf(-x)); }
__device__ __forceinline__ float tanh_(float x) {
    float e = __expf(2.0f * x);
    return (e - 1.0f) / (e + 1.0f);
}

// ---------------------------------------------------------------------------
// Kernel 2: persistent LSTM recurrence, 256 wgs x 512 threads (1 wg/CU).
// R14 = R13 design (hierarchical poll), compile-fixed:
//  - 8 LEADER WGs (bid%32==0) direct-poll the 2048 {stamp,h} slots (÷32
//    traffic), copy quads to a group-private mirror, drain, sync, publish
//    a 1-dword group flag (value t).
//  - 248 FOLLOWERS poll only their group flag (same addr all threads ->
//    1 coalesced line/wave/sample), then one dwordx4 from the mirror.
// Rationale: R10's direct poll = 256x512x16B back-to-back sc0sc1 loads
// ~ 7TB/s of L3 poll traffic (FETCH 137KB/step vs 8KB real data) —
// detect latency was congestion-inflated. Safety: flag-after-drain (R6
// pattern); mirror/flag parity-double-buffered + monotonic; overwrite at
// t+2 gated by all WGs completing t+1 (same induction as hslot). shh16
// double-buffered (staged-h reuse race). Weights stay in LDS (R11 lesson).
// ---------------------------------------------------------------------------
__global__ __launch_bounds__(512, 1) void lstm_recur(
    const float* __restrict__ Whh, const float* __restrict__ xg,
    const float* __restrict__ Wtag, const float* __restrict__ btag,
    unsigned int* __restrict__ hslot, unsigned int* __restrict__ mirror,
    unsigned int* __restrict__ gflag, float* __restrict__ tags,
    float* __restrict__ out, int* __restrict__ flags)
{
    __shared__ __align__(16) ushort wf16[8][4][HID];  // 128 KB f16 weights
    __shared__ __align__(16) ushort shh16[2][HID];    // 8 KB staged h (dbuf)
    __shared__ float sh_red[8];

    const int tid = threadIdx.x;
    const int wv  = tid >> 6;              // wave 0..7
    const int l   = tid & 63;              // lane
    const int bid = blockIdx.x;
    const int j   = 8 * bid + wv;          // hidden unit owned by this wave
    const int grp = bid >> 5;              // leader group 0..7
    const bool leader = (bid & 31) == 0;

    // One-time: W_hh rows -> f16 -> LDS. Lane l owns 8-elem chunks c8=l+64i.
    #pragma unroll
    for (int q = 0; q < 4; ++q) {
        const float* wr = Whh + (size_t)(q * HID + j) * HID;
        #pragma unroll
        for (int i = 0; i < 4; ++i) {
            const int c8 = l + 64 * i;
            float4 va = *(const float4*)(wr + 8 * c8);
            float4 vb = *(const float4*)(wr + 8 * c8 + 4);
            h4v wa = {(_Float16)va.x, (_Float16)va.y, (_Float16)va.z, (_Float16)va.w};
            h4v wb = {(_Float16)vb.x, (_Float16)vb.y, (_Float16)vb.z, (_Float16)vb.w};
            *(h4v*)&wf16[wv][q][8 * c8]     = wa;
            *(h4v*)&wf16[wv][q][8 * c8 + 4] = wb;
        }
    }

    // Hierarchical poll+stage into shh16[buf].
    auto poll_stage = [&](int target, int parity, int buf) {
        unsigned int* mir = mirror + (size_t)(parity * NGRP + grp) * HID;
        unsigned int* fl  = gflag + (parity * NGRP + grp) * 16;
        if (leader) {
            const unsigned int* base = hslot + parity * HID + 4 * tid;
            const ushort tgt = (ushort)target;
            uint4 d;
            for (;;) {
                d = ld_u4_l3(base);
                if ((((ushort)(d.x >> 16)) == tgt) & (((ushort)(d.y >> 16)) == tgt) &
                    (((ushort)(d.z >> 16)) == tgt) & (((ushort)(d.w >> 16)) == tgt))
                    break;
            }
            st_u4_l3(mir + 4 * tid, d);            // re-publish for followers
            ushort4 hh = {(ushort)d.x, (ushort)d.y, (ushort)d.z, (ushort)d.w};
            *(ushort4*)&shh16[buf][4 * tid] = hh;
            wait_vm0();                            // drain mirror stores
            __syncthreads();
            if (tid == 0) st_u32_l3(fl, (unsigned int)target);
        } else {
            for (;;) {
                if (ld_i32_l3(fl) >= target) break;
            }
            uint4 d = ld_u4_l3(mir + 4 * tid);     // fresh: flag after drain
            ushort4 hh = {(ushort)d.x, (ushort)d.y, (ushort)d.z, (ushort)d.w};
            *(ushort4*)&shh16[buf][4 * tid] = hh;
            __syncthreads();
        }
    };

    float cst = 0.0f;
    float xg0 = xg[j], xg1 = xg[j + HID], xg2 = xg[j + 2 * HID], xg3 = xg[j + 3 * HID];

    for (int t = 0; t < SEQL; ++t) {
        const int buf = t & 1;
        if (t > 0) poll_stage(t, (t - 1) & 1, buf);
        else       __syncthreads();        // weights-in-LDS ready

        // Prefetch next step's xg; completes during the dot compute.
        const int tn = (t + 1 < SEQL) ? t + 1 : t;
        const size_t xb = (size_t)tn * G4 + j;
        const float nx0 = xg[xb];
        const float nx1 = xg[xb + HID];
        const float nx2 = xg[xb + 2 * HID];
        const float nx3 = xg[xb + 3 * HID];

        float s0 = 0.f, s1 = 0.f, s2 = 0.f, s3 = 0.f;
        if (t > 0) {
            #pragma unroll
            for (int r = 0; r < 4; ++r) {
                const int kc = 8 * (l + 64 * r);
                h4v ha = *(const h4v*)&shh16[buf][kc];
                h4v hb = *(const h4v*)&shh16[buf][kc + 4];
                h2v h0 = SH2(ha, 0, 1), h1 = SH2(ha, 2, 3);
                h2v h2 = SH2(hb, 0, 1), h3 = SH2(hb, 2, 3);
                h4v w;
                w = *(const h4v*)&wf16[wv][0][kc];
                s0 = DOT2(SH2(w,0,1), h0, s0); s0 = DOT2(SH2(w,2,3), h1, s0);
                w = *(const h4v*)&wf16[wv][0][kc + 4];
                s0 = DOT2(SH2(w,0,1), h2, s0); s0 = DOT2(SH2(w,2,3), h3, s0);
                w = *(const h4v*)&wf16[wv][1][kc];
                s1 = DOT2(SH2(w,0,1), h0, s1); s1 = DOT2(SH2(w,2,3), h1, s1);
                w = *(const h4v*)&wf16[wv][1][kc + 4];
                s1 = DOT2(SH2(w,0,1), h2, s1); s1 = DOT2(SH2(w,2,3), h3, s1);
                w = *(const h4v*)&wf16[wv][2][kc];
                s2 = DOT2(SH2(w,0,1), h0, s2); s2 = DOT2(SH2(w,2,3), h1, s2);
                w = *(const h4v*)&wf16[wv][2][kc + 4];
                s2 = DOT2(SH2(w,0,1), h2, s2); s2 = DOT2(SH2(w,2,3), h3, s2);
                w = *(const h4v*)&wf16[wv][3][kc];
                s3 = DOT2(SH2(w,0,1), h0, s3); s3 = DOT2(SH2(w,2,3), h1, s3);
                w = *(const h4v*)&wf16[wv][3][kc + 4];
                s3 = DOT2(SH2(w,0,1), h2, s3); s3 = DOT2(SH2(w,2,3), h3, s3);
            }
        }
        #pragma unroll
        for (int m = 1; m < 64; m <<= 1) {
            s0 += __shfl_xor(s0, m);
            s1 += __shfl_xor(s1, m);
            s2 += __shfl_xor(s2, m);
            s3 += __shfl_xor(s3, m);
        }
        const float gi = sigm_(s0 + xg0);
        const float gf = sigm_(s1 + xg1);
        const float gg = tanh_(s2 + xg2);
        const float go = sigm_(s3 + xg3);
        cst = gf * cst + gi * gg;
        const float h = go * tanh_(cst);

        if (l == 0) {
            _Float16 hf = (_Float16)h;
            unsigned int d = ((unsigned int)(ushort)(t + 1) << 16)
                           | (unsigned int)__builtin_bit_cast(ushort, hf);
            st_u32_l3(hslot + (t & 1) * HID + j, d);   // data+stamp, one store
        }

        xg0 = nx0; xg1 = nx1; xg2 = nx2; xg3 = nx3;
    }

    // ---- final h, tag projection (wgs 0..49, one tag row each) ----
    poll_stage(SEQL, (SEQL - 1) & 1, 0);       // stage h_1023 into buf 0
    if (bid < NTAG) {
        h4v hv4 = *(const h4v*)&shh16[0][4 * tid];
        float4 w4 = *(const float4*)(Wtag + (size_t)bid * HID + 4 * tid);
        float part = w4.x * (float)hv4.x + w4.y * (float)hv4.y
                   + w4.z * (float)hv4.z + w4.w * (float)hv4.w;
        #pragma unroll
        for (int m = 1; m < 64; m <<= 1) part += __shfl_xor(part, m);
        if (l == 0) sh_red[wv] = part;
    }
    __syncthreads();
    if (bid < NTAG && tid == 0) {
        float s = 0.f;
        #pragma unroll
        for (int i = 0; i < 8; ++i) s += sh_red[i];
        st_f32_l3(tags + bid, s + btag[bid]);
    }
    wait_vm0();
    __syncthreads();
    if (tid == 0) st_u32_l3((unsigned int*)(flags + bid), 1u);

    // ---- log_softmax on wg 0 ----
    if (bid == 0) {
        for (;;) {
            int ok = 1;
            if (tid < NTAG) ok = (ld_i32_l3(flags + tid) >= 1);
            if (__syncthreads_and(ok)) break;
            __builtin_amdgcn_s_sleep(1);
        }
        if (tid < 64) {
            float v = (tid < NTAG) ? ld_f32_l3(tags + tid) : -3.0e38f;
            float mx = v;
            #pragma unroll
            for (int m = 1; m < 64; m <<= 1) mx = fmaxf(mx, __shfl_xor(mx, m));
            float e = (tid < NTAG) ? __expf(v - mx) : 0.f;
            float se = e;
            #pragma unroll
            for (int m = 1; m < 64; m <<= 1) se += __shfl_xor(se, m);
            if (tid < NTAG) out[tid] = v - mx - __logf(se);
        }
    }
}

// ---------------------------------------------------------------------------
extern "C" void kernel_launch(void* const* d_in, const int* in_sizes, int n_in,
                              void* d_out, int out_size, void* d_ws, size_t ws_size,
                              hipStream_t stream)
{
    const int*   seq  = (const int*)d_in[0];
    const float* emb  = (const float*)d_in[1];
    const float* Wih  = (const float*)d_in[2];
    const float* Whh  = (const float*)d_in[3];
    const float* bih  = (const float*)d_in[4];
    const float* bhh  = (const float*)d_in[5];
    const float* Wtag = (const float*)d_in[6];
    const float* btag = (const float*)d_in[7];
    float* out = (float*)d_out;

    float* xg = (float*)d_ws;                                        // 32 MiB
    unsigned int* hslot  = (unsigned int*)(xg + (size_t)SEQL * G4);  // 2*2048 u32
    unsigned int* mirror = hslot + 2 * HID;                          // 2*8*2048 u32
    unsigned int* gflag  = mirror + 2 * NGRP * HID;                  // 2*8*16 u32
    float* tags  = (float*)(gflag + 2 * NGRP * 16);                  // 64 f32
    int*   flags = (int*)(tags + 64);                                // 256 ints

    dim3 g1(G4 / 128, SEQL / 128);                                   // (64, 8)
    gemm_xgates<<<g1, 256, 0, stream>>>(seq, emb, Wih, bih, bhh, xg,
                                        hslot, gflag, flags);

    void* args[] = {(void*)&Whh, (void*)&xg, (void*)&Wtag, (void*)&btag,
                    (void*)&hslot, (void*)&mirror, (void*)&gflag,
                    (void*)&tags, (void*)&out, (void*)&flags};
    hipLaunchCooperativeKernel((void*)lstm_recur, dim3(NWG), dim3(512),
                               args, 0, stream);
}

// Round 15
// 2973.366 us; speedup vs baseline: 1.7765x; 1.7765x over previous
//
#include <hip/hip_runtime.h>

#define SEQL 1024
#define EMB  2048
#define HID  2048
#define G4   8192   // 4*HID
#define NTAG 50
#define NWG  256

typedef _Float16 h2v __attribute__((ext_vector_type(2)));
typedef _Float16 h4v __attribute__((ext_vector_type(4)));
typedef __attribute__((ext_vector_type(8))) short bf16x8;   // 8 bf16 = 4 VGPR
typedef __attribute__((ext_vector_type(4))) float f32x4;

#if __has_builtin(__builtin_amdgcn_fdot2)
#define DOT2(a, b, c) __builtin_amdgcn_fdot2((a), (b), (c), false)
#else
#define DOT2(a, b, c) ((c) + (float)(a).x * (float)(b).x + (float)(a).y * (float)(b).y)
#endif
#define SH2(v, i, j) __builtin_shufflevector((v), (v), (i), (j))

__device__ __forceinline__ ushort f2bf_rne(float f) {
    unsigned u = __float_as_uint(f);
    unsigned r = (u + 0x7fffu + ((u >> 16) & 1u)) >> 16;   // round-nearest-even
    return (ushort)r;
}

// ---------------------------------------------------------------------------
// Kernel 1: x_gates = emb[seq] @ W_ih^T + b_ih + b_hh  (bf16 MFMA, verified
// ~40us in R10). Block (0,0) zeroes kernel 2's hslot stamps + final flags
// (graph-replay reset; stream-ordered before lstm_recur).
// ---------------------------------------------------------------------------
__global__ __launch_bounds__(256) void gemm_xgates(
    const int* __restrict__ seq, const float* __restrict__ emb,
    const float* __restrict__ Wih, const float* __restrict__ bih,
    const float* __restrict__ bhh, float* __restrict__ xg,
    unsigned int* __restrict__ hslot, int* __restrict__ flags)
{
    if (blockIdx.x == 0 && blockIdx.y == 0) {
        for (int i = threadIdx.x; i < 2 * HID; i += 256) hslot[i] = 0;
        if (threadIdx.x < NWG) flags[threadIdx.x] = 0;
    }

    constexpr int BM = 128, BN = 128, BK = 64;
    __shared__ __align__(16) ushort Al[BM][BK];   // bf16, chunk-XOR swizzled
    __shared__ __align__(16) ushort Bl[BN][BK];
    __shared__ int srow[BM];

    const int tid = threadIdx.x;
    const int bn = blockIdx.x, bm = blockIdx.y;

    if (tid < BM) srow[tid] = seq[bm * BM + tid];
    __syncthreads();

    const int lane = tid & 63;
    const int wave = tid >> 6;          // 0..3
    const int wm = (wave >> 1) * 64;
    const int wn = (wave & 1) * 64;
    const int srw = tid >> 1;           // staging row 0..127
    const int skh = (tid & 1) * 32;     // staging k-offset 0/32
    const int cb  = skh >> 3;           // base chunk 0/4

    f32x4 acc[4][4] = {};

    for (int k0 = 0; k0 < EMB; k0 += BK) {
        const float* ap = emb + (size_t)srow[srw] * EMB + k0 + skh;
        const float* bp = Wih + (size_t)(bn * BN + srw) * EMB + k0 + skh;
        #pragma unroll
        for (int c = 0; c < 4; ++c) {
            float4 a0 = *(const float4*)(ap + 8 * c);
            float4 a1 = *(const float4*)(ap + 8 * c + 4);
            bf16x8 av;
            av[0] = (short)f2bf_rne(a0.x); av[1] = (short)f2bf_rne(a0.y);
            av[2] = (short)f2bf_rne(a0.z); av[3] = (short)f2bf_rne(a0.w);
            av[4] = (short)f2bf_rne(a1.x); av[5] = (short)f2bf_rne(a1.y);
            av[6] = (short)f2bf_rne(a1.z); av[7] = (short)f2bf_rne(a1.w);
            *(bf16x8*)&Al[srw][8 * ((cb + c) ^ (srw & 7))] = av;

            float4 b0 = *(const float4*)(bp + 8 * c);
            float4 b1 = *(const float4*)(bp + 8 * c + 4);
            bf16x8 bv;
            bv[0] = (short)f2bf_rne(b0.x); bv[1] = (short)f2bf_rne(b0.y);
            bv[2] = (short)f2bf_rne(b0.z); bv[3] = (short)f2bf_rne(b0.w);
            bv[4] = (short)f2bf_rne(b1.x); bv[5] = (short)f2bf_rne(b1.y);
            bv[6] = (short)f2bf_rne(b1.z); bv[7] = (short)f2bf_rne(b1.w);
            *(bf16x8*)&Bl[srw][8 * ((cb + c) ^ (srw & 7))] = bv;
        }
        __syncthreads();

        const int kg = lane >> 4;        // k-group 0..3
        #pragma unroll
        for (int ks = 0; ks < 2; ++ks) {
            bf16x8 af[4], bfr[4];
            #pragma unroll
            for (int f = 0; f < 4; ++f) {
                const int ra = wm + f * 16 + (lane & 15);
                af[f]  = *(const bf16x8*)&Al[ra][8 * ((ks * 4 + kg) ^ (ra & 7))];
                const int rb = wn + f * 16 + (lane & 15);
                bfr[f] = *(const bf16x8*)&Bl[rb][8 * ((ks * 4 + kg) ^ (rb & 7))];
            }
            #pragma unroll
            for (int i = 0; i < 4; ++i)
                #pragma unroll
                for (int j2 = 0; j2 < 4; ++j2)
                    acc[i][j2] = __builtin_amdgcn_mfma_f32_16x16x32_bf16(
                        af[i], bfr[j2], acc[i][j2], 0, 0, 0);
        }
        __syncthreads();
    }

    float bb[4];
    #pragma unroll
    for (int j2 = 0; j2 < 4; ++j2) {
        const int col = bn * BN + wn + j2 * 16 + (lane & 15);
        bb[j2] = bih[col] + bhh[col];
    }
    #pragma unroll
    for (int i = 0; i < 4; ++i) {
        #pragma unroll
        for (int e = 0; e < 4; ++e) {
            const int row = bm * BM + wm + i * 16 + (lane >> 4) * 4 + e;
            #pragma unroll
            for (int j2 = 0; j2 < 4; ++j2) {
                const int col = bn * BN + wn + j2 * 16 + (lane & 15);
                xg[(size_t)row * G4 + col] = acc[i][j2][e] + bb[j2];
            }
        }
    }
}

// ---------------------------------------------------------------------------
// L3-direct (sc0 sc1) helpers — data at the coherence point, zero cache
// maintenance. (Compiler notes R12/R13: uint4 ok as asm OUTPUT, not input.)
// ---------------------------------------------------------------------------
__device__ __forceinline__ uint4 ld_u4_l3(const void* p) {
    uint4 r;
    asm volatile("global_load_dwordx4 %0, %1, off sc0 sc1\n\ts_waitcnt vmcnt(0)"
                 : "=v"(r) : "v"(p) : "memory");
    return r;
}
__device__ __forceinline__ int ld_i32_l3(const void* p) {
    int r;
    asm volatile("global_load_dword %0, %1, off sc0 sc1\n\ts_waitcnt vmcnt(0)"
                 : "=v"(r) : "v"(p) : "memory");
    return r;
}
__device__ __forceinline__ float ld_f32_l3(const void* p) {
    float r;
    asm volatile("global_load_dword %0, %1, off sc0 sc1\n\ts_waitcnt vmcnt(0)"
                 : "=v"(r) : "v"(p) : "memory");
    return r;
}
__device__ __forceinline__ void st_u32_l3(void* p, unsigned int v) {
    asm volatile("global_store_dword %0, %1, off sc0 sc1"
                 :: "v"(p), "v"(v) : "memory");
}
__device__ __forceinline__ void st_f32_l3(void* p, float v) {
    asm volatile("global_store_dword %0, %1, off sc0 sc1"
                 :: "v"(p), "v"(v) : "memory");
}
__device__ __forceinline__ void wait_vm0() {
    asm volatile("s_waitcnt vmcnt(0)" ::: "memory");
}

__device__ __forceinline__ float sigm_(float x) { return 1.0f / (1.0f + __expf(-x)); }
__device__ __forceinline__ float tanh_(float x) {
    float e = __expf(2.0f * x);
    return (e - 1.0f) / (e + 1.0f);
}

// ---------------------------------------------------------------------------
// Kernel 2: persistent LSTM recurrence, 256 wgs x 512 threads (1 wg/CU).
// == R10 structure (best verified: 2.73us/step) + shh16 parity double-buffer.
// f16 weights in LDS (128 KB); v_dot2_f32_f16 dots; cross-WG exchange is ONE
// dword per unit {stamp:u16=t+1, h:f16} (no data/flag tear); independent
// per-thread spin (back-to-back sc0sc1 dwordx4, period = 1 L3 RT).
// Lessons encoded: R11 (reg-weights spill, LDS read is hidden), R12-R14
// (deeper poll / hierarchy add chain depth or traffic and lose - the flat
// protocol is latency-optimal at ~2 L3 RTs/step).
// shh16[2]: thread at iter t+1 writes buf (t+1)&1 while slow waves may still
// read buf t&1 -> disjoint; reuse of buf t&1 at t+2 is gated through all
// stamps t+2 which require every wave DONE reading at t (publish-after-read).
// ---------------------------------------------------------------------------
__global__ __launch_bounds__(512, 1) void lstm_recur(
    const float* __restrict__ Whh, const float* __restrict__ xg,
    const float* __restrict__ Wtag, const float* __restrict__ btag,
    unsigned int* __restrict__ hslot, float* __restrict__ tags,
    float* __restrict__ out, int* __restrict__ flags)
{
    __shared__ __align__(16) ushort wf16[8][4][HID];  // 128 KB f16 weights
    __shared__ __align__(16) ushort shh16[2][HID];    // 8 KB staged h (dbuf)
    __shared__ float sh_red[8];

    const int tid = threadIdx.x;
    const int wv  = tid >> 6;              // wave 0..7
    const int l   = tid & 63;              // lane
    const int bid = blockIdx.x;
    const int j   = 8 * bid + wv;          // hidden unit owned by this wave

    // One-time: W_hh rows -> f16 -> LDS. Lane l owns 8-elem chunks c8=l+64i.
    #pragma unroll
    for (int q = 0; q < 4; ++q) {
        const float* wr = Whh + (size_t)(q * HID + j) * HID;
        #pragma unroll
        for (int i = 0; i < 4; ++i) {
            const int c8 = l + 64 * i;
            float4 va = *(const float4*)(wr + 8 * c8);
            float4 vb = *(const float4*)(wr + 8 * c8 + 4);
            h4v wa = {(_Float16)va.x, (_Float16)va.y, (_Float16)va.z, (_Float16)va.w};
            h4v wb = {(_Float16)vb.x, (_Float16)vb.y, (_Float16)vb.z, (_Float16)vb.w};
            *(h4v*)&wf16[wv][q][8 * c8]     = wa;
            *(h4v*)&wf16[wv][q][8 * c8 + 4] = wb;
        }
    }

    // Independent spin until this thread's 4 stamps == target, then stage h
    // into shh16[buf] and converge with a single syncthreads.
    auto poll_stage = [&](int target, int parity, int buf) {
        const unsigned int* base = hslot + parity * HID + 4 * tid;
        const ushort tgt = (ushort)target;
        uint4 d;
        for (;;) {
            d = ld_u4_l3(base);
            if ((((ushort)(d.x >> 16)) == tgt) & (((ushort)(d.y >> 16)) == tgt) &
                (((ushort)(d.z >> 16)) == tgt) & (((ushort)(d.w >> 16)) == tgt))
                break;
        }
        ushort4 hh = {(ushort)d.x, (ushort)d.y, (ushort)d.z, (ushort)d.w};
        *(ushort4*)&shh16[buf][4 * tid] = hh;      // 8B ds_write, contiguous
        __syncthreads();
    };

    float cst = 0.0f;
    float xg0 = xg[j], xg1 = xg[j + HID], xg2 = xg[j + 2 * HID], xg3 = xg[j + 3 * HID];

    for (int t = 0; t < SEQL; ++t) {
        const int buf = t & 1;
        if (t > 0) poll_stage(t, (t - 1) & 1, buf);
        else       __syncthreads();            // weights-in-LDS ready

        // Prefetch next step's xg; completes during the dot compute.
        const int tn = (t + 1 < SEQL) ? t + 1 : t;
        const size_t xb = (size_t)tn * G4 + j;
        const float nx0 = xg[xb];
        const float nx1 = xg[xb + HID];
        const float nx2 = xg[xb + 2 * HID];
        const float nx3 = xg[xb + 3 * HID];

        float s0 = 0.f, s1 = 0.f, s2 = 0.f, s3 = 0.f;
        if (t > 0) {
            #pragma unroll
            for (int r = 0; r < 4; ++r) {
                const int kc = 8 * (l + 64 * r);
                h4v ha = *(const h4v*)&shh16[buf][kc];
                h4v hb = *(const h4v*)&shh16[buf][kc + 4];
                h2v h0 = SH2(ha, 0, 1), h1 = SH2(ha, 2, 3);
                h2v h2 = SH2(hb, 0, 1), h3 = SH2(hb, 2, 3);
                h4v w;
                w = *(const h4v*)&wf16[wv][0][kc];
                s0 = DOT2(SH2(w,0,1), h0, s0); s0 = DOT2(SH2(w,2,3), h1, s0);
                w = *(const h4v*)&wf16[wv][0][kc + 4];
                s0 = DOT2(SH2(w,0,1), h2, s0); s0 = DOT2(SH2(w,2,3), h3, s0);
                w = *(const h4v*)&wf16[wv][1][kc];
                s1 = DOT2(SH2(w,0,1), h0, s1); s1 = DOT2(SH2(w,2,3), h1, s1);
                w = *(const h4v*)&wf16[wv][1][kc + 4];
                s1 = DOT2(SH2(w,0,1), h2, s1); s1 = DOT2(SH2(w,2,3), h3, s1);
                w = *(const h4v*)&wf16[wv][2][kc];
                s2 = DOT2(SH2(w,0,1), h0, s2); s2 = DOT2(SH2(w,2,3), h1, s2);
                w = *(const h4v*)&wf16[wv][2][kc + 4];
                s2 = DOT2(SH2(w,0,1), h2, s2); s2 = DOT2(SH2(w,2,3), h3, s2);
                w = *(const h4v*)&wf16[wv][3][kc];
                s3 = DOT2(SH2(w,0,1), h0, s3); s3 = DOT2(SH2(w,2,3), h1, s3);
                w = *(const h4v*)&wf16[wv][3][kc + 4];
                s3 = DOT2(SH2(w,0,1), h2, s3); s3 = DOT2(SH2(w,2,3), h3, s3);
            }
        }
        #pragma unroll
        for (int m = 1; m < 64; m <<= 1) {
            s0 += __shfl_xor(s0, m);
            s1 += __shfl_xor(s1, m);
            s2 += __shfl_xor(s2, m);
            s3 += __shfl_xor(s3, m);
        }
        const float gi = sigm_(s0 + xg0);
        const float gf = sigm_(s1 + xg1);
        const float gg = tanh_(s2 + xg2);
        const float go = sigm_(s3 + xg3);
        cst = gf * cst + gi * gg;
        const float h = go * tanh_(cst);

        if (l == 0) {
            _Float16 hf = (_Float16)h;
            unsigned int d = ((unsigned int)(ushort)(t + 1) << 16)
                           | (unsigned int)__builtin_bit_cast(ushort, hf);
            st_u32_l3(hslot + (t & 1) * HID + j, d);   // data+stamp, one store
        }

        xg0 = nx0; xg1 = nx1; xg2 = nx2; xg3 = nx3;
    }

    // ---- final h, tag projection (wgs 0..49, one tag row each) ----
    poll_stage(SEQL, (SEQL - 1) & 1, 0);       // stage h_1023 into buf 0
    if (bid < NTAG) {
        h4v hv4 = *(const h4v*)&shh16[0][4 * tid];
        float4 w4 = *(const float4*)(Wtag + (size_t)bid * HID + 4 * tid);
        float part = w4.x * (float)hv4.x + w4.y * (float)hv4.y
                   + w4.z * (float)hv4.z + w4.w * (float)hv4.w;
        #pragma unroll
        for (int m = 1; m < 64; m <<= 1) part += __shfl_xor(part, m);
        if (l == 0) sh_red[wv] = part;
    }
    __syncthreads();
    if (bid < NTAG && tid == 0) {
        float s = 0.f;
        #pragma unroll
        for (int i = 0; i < 8; ++i) s += sh_red[i];
        st_f32_l3(tags + bid, s + btag[bid]);
    }
    wait_vm0();
    __syncthreads();
    if (tid == 0) st_u32_l3((unsigned int*)(flags + bid), 1u);

    // ---- log_softmax on wg 0 ----
    if (bid == 0) {
        for (;;) {
            int ok = 1;
            if (tid < NTAG) ok = (ld_i32_l3(flags + tid) >= 1);
            if (__syncthreads_and(ok)) break;
            __builtin_amdgcn_s_sleep(1);
        }
        if (tid < 64) {
            float v = (tid < NTAG) ? ld_f32_l3(tags + tid) : -3.0e38f;
            float mx = v;
            #pragma unroll
            for (int m = 1; m < 64; m <<= 1) mx = fmaxf(mx, __shfl_xor(mx, m));
            float e = (tid < NTAG) ? __expf(v - mx) : 0.f;
            float se = e;
            #pragma unroll
            for (int m = 1; m < 64; m <<= 1) se += __shfl_xor(se, m);
            if (tid < NTAG) out[tid] = v - mx - __logf(se);
        }
    }
}

// ---------------------------------------------------------------------------
extern "C" void kernel_launch(void* const* d_in, const int* in_sizes, int n_in,
                              void* d_out, int out_size, void* d_ws, size_t ws_size,
                              hipStream_t stream)
{
    const int*   seq  = (const int*)d_in[0];
    const float* emb  = (const float*)d_in[1];
    const float* Wih  = (const float*)d_in[2];
    const float* Whh  = (const float*)d_in[3];
    const float* bih  = (const float*)d_in[4];
    const float* bhh  = (const float*)d_in[5];
    const float* Wtag = (const float*)d_in[6];
    const float* btag = (const float*)d_in[7];
    float* out = (float*)d_out;

    float* xg = (float*)d_ws;                              // 32 MiB
    unsigned int* hslot = (unsigned int*)(xg + (size_t)SEQL * G4);  // 2*2048 u32
    float* tags  = (float*)(hslot + 2 * HID);              // 50 f32 (pad 64)
    int*   flags = (int*)(tags + 64);                      // 256 ints

    dim3 g1(G4 / 128, SEQL / 128);                         // (64, 8)
    gemm_xgates<<<g1, 256, 0, stream>>>(seq, emb, Wih, bih, bhh, xg, hslot, flags);

    void* args[] = {(void*)&Whh, (void*)&xg, (void*)&Wtag, (void*)&btag,
                    (void*)&hslot, (void*)&tags, (void*)&out, (void*)&flags};
    hipLaunchCooperativeKernel((void*)lstm_recur, dim3(NWG), dim3(512),
                               args, 0, stream);
}